// Round 15
// baseline (339.886 us; speedup 1.0000x reference)
//
#include <hip/hip_runtime.h>
#include <hip/hip_bf16.h>

#define NB 8
#define NS 4096
#define NE 2048
#define NL 64
#define NH 128
#define NM (NB*NS)

typedef unsigned short ushort_t;
typedef __attribute__((ext_vector_type(4))) float f32x4;
typedef __attribute__((ext_vector_type(8))) __bf16 bf16x8;
typedef __attribute__((ext_vector_type(8))) unsigned short u16x8;
typedef __attribute__((ext_vector_type(4))) unsigned short u16x4;

// 128^-0.5 * log2(e): folded into absorbed-q weights so attn uses exp2 directly
#define SCALE2 0.1275174537f

__device__ __forceinline__ float fast_exp2(float x) {
    return __builtin_amdgcn_exp2f(x);   // v_exp_f32: D = 2^S0
}

__device__ __forceinline__ unsigned short f2bf(float f) {
    union { float f; unsigned u; } v; v.f = f;
    unsigned u = v.u + 0x7fffu + ((v.u >> 16) & 1u);
    return (unsigned short)(u >> 16);
}

__device__ __forceinline__ float bf2f(ushort_t u) {
    union { unsigned u; float f; } v; v.u = (unsigned)u << 16; return v.f;
}

// XOR swizzle for 128-byte-stride LDS tiles (G4)
__device__ __forceinline__ int swz(int row, int colbyte) {
    return (row * 128 + colbyte) ^ ((row & 7) << 4);
}

// Raw barrier: LDS visibility only — does NOT drain vmcnt (T4).
__device__ __forceinline__ void wg_barrier() {
    asm volatile("s_waitcnt lgkmcnt(0)" ::: "memory");
    __builtin_amdgcn_s_barrier();
    __builtin_amdgcn_sched_barrier(0);
}

// ---------------------------------------------------------------------------
// prep: WcatT[128][2048] bf16.  rows 0..63 = W_dkv, rows 64..127 = absorbed^T * SCALE2
// ---------------------------------------------------------------------------
__global__ __launch_bounds__(256) void prep_kernel(
    const float* __restrict__ Wdkv, const float* __restrict__ Wk,
    const float* __restrict__ Wq, ushort_t* __restrict__ WcatT)
{
    __shared__ float wk[128 * 64];
    const int t = threadIdx.x;
    for (int i = t; i < 128 * 64; i += 256) wk[i] = Wk[i];
    __syncthreads();
    const int e = blockIdx.x * 256 + t;
    const int l0 = blockIdx.y * 16;
    float acc[16];
    #pragma unroll
    for (int l = 0; l < 16; ++l) acc[l] = 0.f;
    for (int h = 0; h < 128; ++h) {
        float q = Wq[h * NE + e];
        #pragma unroll
        for (int l = 0; l < 16; ++l) acc[l] += q * wk[h * 64 + l0 + l];
    }
    for (int l = 0; l < 16; ++l) WcatT[(64 + l0 + l) * NE + e] = f2bf(acc[l] * SCALE2);
    for (int l = 0; l < 16; ++l) WcatT[(l0 + l) * NE + e] = f2bf(Wdkv[(l0 + l) * NE + e]);
}

// ---------------------------------------------------------------------------
// proj: Y[M,128] = x[M,2048] @ WcatT^T.  BM=64,BN=128,BK=64, 4 waves (2x2).
// Depth-2 ping-pong register prefetch + raw barriers.
// Epilogue: latent(f32) + k(bf16) + q(bf16) + kt = latent^T (identity MFMA).
// (Measured R11: ~50 us, ~90% of its 45 us HBM floor — frozen.)
// ---------------------------------------------------------------------------
__global__ __launch_bounds__(256) void proj_kernel(
    const float* __restrict__ x, const ushort_t* __restrict__ WcatT,
    float* __restrict__ latent_out, ushort_t* __restrict__ k_bf,
    ushort_t* __restrict__ q_bf, ushort_t* __restrict__ kt)
{
    __shared__ ushort_t As[2][64 * 64];
    __shared__ ushort_t Bs[2][128 * 64];
    const int tid = threadIdx.x;
    const int w = tid >> 6, lane = tid & 63, lg = lane >> 4, li = lane & 15;
    const int m0 = blockIdx.x * 64;
    const int wm = (w >> 1) * 32, wn = (w & 1) * 64;
    const int srow = tid >> 3, scol = tid & 7;

    f32x4 acc[2][4];
    #pragma unroll
    for (int i = 0; i < 2; ++i)
        #pragma unroll
        for (int j = 0; j < 4; ++j) acc[i][j] = f32x4{0.f, 0.f, 0.f, 0.f};

    f32x4 a0reg[2][2], a1reg[2][2];
    u16x8 b0reg[4], b1reg[4];

#define PLOAD(k0, AR, BR) do { \
    _Pragma("unroll") for (int p = 0; p < 2; ++p) { \
        const float* gp = x + (long)(m0 + srow + 32 * p) * NE + (k0) + scol * 8; \
        AR[p][0] = *reinterpret_cast<const f32x4*>(gp); \
        AR[p][1] = *reinterpret_cast<const f32x4*>(gp + 4); } \
    _Pragma("unroll") for (int p = 0; p < 4; ++p) \
        BR[p] = *reinterpret_cast<const u16x8*>(WcatT + (long)(srow + 32 * p) * NE + (k0) + scol * 8); \
} while (0)

#define PWRITE(AR, BR, buf) do { \
    _Pragma("unroll") for (int p = 0; p < 2; ++p) { \
        union { unsigned uw[4]; u16x8 v; } hu; \
        asm("v_cvt_pk_bf16_f32 %0, %1, %2" : "=v"(hu.uw[0]) : "v"(AR[p][0][0]), "v"(AR[p][0][1])); \
        asm("v_cvt_pk_bf16_f32 %0, %1, %2" : "=v"(hu.uw[1]) : "v"(AR[p][0][2]), "v"(AR[p][0][3])); \
        asm("v_cvt_pk_bf16_f32 %0, %1, %2" : "=v"(hu.uw[2]) : "v"(AR[p][1][0]), "v"(AR[p][1][1])); \
        asm("v_cvt_pk_bf16_f32 %0, %1, %2" : "=v"(hu.uw[3]) : "v"(AR[p][1][2]), "v"(AR[p][1][3])); \
        *reinterpret_cast<u16x8*>(reinterpret_cast<char*>(As[buf]) + swz(srow + 32 * p, scol * 16)) = hu.v; } \
    _Pragma("unroll") for (int p = 0; p < 4; ++p) \
        *reinterpret_cast<u16x8*>(reinterpret_cast<char*>(Bs[buf]) + swz(srow + 32 * p, scol * 16)) = BR[p]; \
} while (0)

    auto compute = [&](int buf) {
        #pragma unroll
        for (int c = 0; c < 2; ++c) {
            bf16x8 af[2], bfv[4];
            #pragma unroll
            for (int mf = 0; mf < 2; ++mf)
                af[mf] = *reinterpret_cast<const bf16x8*>(
                    reinterpret_cast<const char*>(As[buf]) + swz(wm + 16 * mf + li, c * 64 + lg * 16));
            #pragma unroll
            for (int nf = 0; nf < 4; ++nf)
                bfv[nf] = *reinterpret_cast<const bf16x8*>(
                    reinterpret_cast<const char*>(Bs[buf]) + swz(wn + 16 * nf + li, c * 64 + lg * 16));
            #pragma unroll
            for (int mf = 0; mf < 2; ++mf)
                #pragma unroll
                for (int nf = 0; nf < 4; ++nf)
                    acc[mf][nf] = __builtin_amdgcn_mfma_f32_16x16x32_bf16(
                        af[mf], bfv[nf], acc[mf][nf], 0, 0, 0);
        }
    };

    PLOAD(0, a0reg, b0reg);
    PLOAD(64, a1reg, b1reg);
    PWRITE(a0reg, b0reg, 0);
    wg_barrier();

    for (int ks = 0; ks < 32; ks += 2) {
        if (ks + 2 < 32) PLOAD((ks + 2) * 64, a0reg, b0reg);
        compute(0);
        PWRITE(a1reg, b1reg, 1);
        wg_barrier();
        if (ks + 3 < 32) PLOAD((ks + 3) * 64, a1reg, b1reg);
        compute(1);
        if (ks + 2 < 32) PWRITE(a0reg, b0reg, 0);
        wg_barrier();
    }

    const int b = m0 >> 12, s0 = m0 & 4095;
    #pragma unroll
    for (int mf = 0; mf < 2; ++mf) {
        #pragma unroll
        for (int nf = 0; nf < 4; ++nf) {
            int col = wn + 16 * nf + li;
            #pragma unroll
            for (int r = 0; r < 4; ++r) {
                int row = m0 + wm + 16 * mf + 4 * lg + r;
                float v = acc[mf][nf][r];
                if (wn == 0) {
                    latent_out[(long)row * NL + col] = v;
                    k_bf[(long)row * NL + col] = f2bf(v);
                    *reinterpret_cast<ushort_t*>(reinterpret_cast<char*>(As[0]) +
                        swz(wm + 16 * mf + 4 * lg + r, col * 2)) = f2bf(v);
                } else {
                    q_bf[(long)row * NL + (col - 64)] = f2bf(v);
                }
            }
        }
    }
    wg_barrier();
    // kt-GEMM: kt[l][s] = latent^T via A = identity fragment.
    union { u16x8 u; bf16x8 v; } iu;
    #pragma unroll
    for (int j = 0; j < 8; ++j)
        iu.u[j] = (lg == (li >> 3) + 2 * (w & 1) && (li & 7) == j)
                      ? (ushort_t)0x3F80 : (ushort_t)0;
    const int ckt = w >> 1;
    f32x4 ktacc[4];
    #pragma unroll
    for (int nf = 0; nf < 4; ++nf) {
        bf16x8 bfv = *reinterpret_cast<const bf16x8*>(
            reinterpret_cast<const char*>(As[0]) + swz(16 * nf + li, ckt * 64 + lg * 16));
        ktacc[nf] = __builtin_amdgcn_mfma_f32_16x16x32_bf16(
            iu.v, bfv, f32x4{0.f, 0.f, 0.f, 0.f}, 0, 0, 0);
    }
    #pragma unroll
    for (int nf = 0; nf < 4; ++nf)
        #pragma unroll
        for (int r = 0; r < 4; ++r)
            kt[(long)(b * 64 + 16 * w + 4 * lg + r) * NS + s0 + 16 * nf + li] =
                f2bf(ktacc[nf][r]);
}

// ---------------------------------------------------------------------------
// attn: R9 math/layouts, OCCUPANCY-FIXED: single-buffered Ks(16K)+KTs(16K)
// with T14 issue-early/write-late staging (2 barriers/chunk); 34.8KB static
// LDS + __launch_bounds__(256,4) -> 4 blocks/CU, 16 waves/CU (was 2/8).
// kv-split across waves; in-block shard merge; fused Wv out-GEMM.
// ---------------------------------------------------------------------------
__global__ __launch_bounds__(256, 4) void attn_kernel(
    const ushort_t* __restrict__ q_bf, const ushort_t* __restrict__ k_bf,
    const ushort_t* __restrict__ kt, const float* __restrict__ Wv,
    float* __restrict__ out)
{
    __shared__ __attribute__((aligned(16))) char smem[34816];
    // main loop: Ks @ 0 (16K, [128][64] swizzled); KTs @ 16K (16K, [64][128] kv'-permuted)
    // epilogue:  OW bf16 [4][64][64] @ 0 (32K); mw @ 32768; lw @ 33792
    //            then (after read-fence): Ms @ 0 (8K); Wvs @ 8192 (16K)
    //            then Os f32 [64][132] @ 0 (33792 B)
    ushort_t* OW = (ushort_t*)smem;
    float* mw = (float*)(smem + 32768);
    float* lw = (float*)(smem + 33792);
    ushort_t* Ms = (ushort_t*)smem;
    ushort_t* Wvs = (ushort_t*)(smem + 8192);
    float* Os = (float*)smem;

    const int tid = threadIdx.x;
    const int w = tid >> 6, lane = tid & 63, lg = lane >> 4, li = lane & 15;
    const int l = blockIdx.x;
    const int b = l & 7;
    const int p_ = l >> 3;
    // balanced qt permutation (R5-validated under both XCD dispatch policies)
    const int k_ = p_ >> 1, e_ = p_ & 1, kk = (k_ & 15) * 2;
    const int qt = (k_ >> 4) ? (e_ ? kk + 1 : 63 - kk) : (e_ ? 62 - kk : kk);
    const int Q0 = qt << 6;
    const int nch = (qt >> 1) + 1;       // 128-kv chunks

    const int krow = tid >> 1, khalf = tid & 1;      // K: [128][64]
    const int trow = tid >> 2, tkq = (tid & 3) * 32; // KT: [64][128]

    bf16x8 qf[4][2];
    #pragma unroll
    for (int qb = 0; qb < 4; ++qb)
        #pragma unroll
        for (int c = 0; c < 2; ++c)
            qf[qb][c] = *reinterpret_cast<const bf16x8*>(
                q_bf + ((long)b * NS + Q0 + 16 * qb + li) * NL + c * 32 + lg * 8);

    float m_r[4], l_r[4];
    #pragma unroll
    for (int qb = 0; qb < 4; ++qb) { m_r[qb] = -1.0e30f; l_r[qb] = 0.f; }
    f32x4 oacc[4][4];
    #pragma unroll
    for (int qb = 0; qb < 4; ++qb)
        #pragma unroll
        for (int n = 0; n < 4; ++n) oacc[qb][n] = f32x4{0.f, 0.f, 0.f, 0.f};

    u16x8 kreg[4], treg[4];   // single staging set (T14 issue-early/write-late)

#define ALOAD(ch) do { \
    const int kv0_ = (ch) * 128; \
    _Pragma("unroll") for (int pp = 0; pp < 4; ++pp) \
        kreg[pp] = *reinterpret_cast<const u16x8*>( \
            k_bf + ((long)b * NS + kv0_ + krow) * NL + khalf * 32 + pp * 8); \
    _Pragma("unroll") for (int pp = 0; pp < 4; ++pp) \
        treg[pp] = *reinterpret_cast<const u16x8*>( \
            kt + ((long)b * 64 + trow) * NS + kv0_ + tkq + pp * 8); \
} while (0)

#define AWRITE() do { \
    char* Kb_ = smem; \
    char* Tb_ = smem + 16384; \
    _Pragma("unroll") for (int pp = 0; pp < 4; ++pp) \
        *reinterpret_cast<u16x8*>(Kb_ + swz(krow, khalf * 64 + pp * 16)) = kreg[pp]; \
    _Pragma("unroll") for (int pp = 0; pp < 4; ++pp) { \
        const int kv8 = tkq + pp * 8; \
        const int colp = (kv8 & 0x60) | ((kv8 & 0xC) << 1) | ((kv8 & 0x10) >> 2); \
        const int xo = (trow & 15) << 4; \
        u16x4 lo = {treg[pp][0], treg[pp][1], treg[pp][2], treg[pp][3]}; \
        u16x4 hi = {treg[pp][4], treg[pp][5], treg[pp][6], treg[pp][7]}; \
        *reinterpret_cast<u16x4*>(Tb_ + trow * 256 + ((colp * 2) ^ xo)) = lo; \
        *reinterpret_cast<u16x4*>(Tb_ + trow * 256 + (((colp + 8) * 2) ^ xo)) = hi; \
    } \
} while (0)

    auto compute = [&](bool diag, int kv0) {
        const char* Kb = smem;
        const char* Tb = smem + 16384;
        f32x4 s[2][4];
        #pragma unroll
        for (int kvb = 0; kvb < 2; ++kvb)
            #pragma unroll
            for (int qb = 0; qb < 4; ++qb) s[kvb][qb] = f32x4{0.f, 0.f, 0.f, 0.f};
        __builtin_amdgcn_s_setprio(1);
        #pragma unroll
        for (int c = 0; c < 2; ++c)
            #pragma unroll
            for (int kvb = 0; kvb < 2; ++kvb) {
                bf16x8 a = *reinterpret_cast<const bf16x8*>(
                    Kb + swz(32 * w + 16 * kvb + li, c * 64 + lg * 16));
                #pragma unroll
                for (int qb = 0; qb < 4; ++qb)
                    s[kvb][qb] = __builtin_amdgcn_mfma_f32_16x16x32_bf16(
                        a, qf[qb][c], s[kvb][qb], 0, 0, 0);
            }
        __builtin_amdgcn_s_setprio(0);
        if (diag) {
            #pragma unroll
            for (int kvb = 0; kvb < 2; ++kvb)
                #pragma unroll
                for (int qb = 0; qb < 4; ++qb)
                    #pragma unroll
                    for (int r = 0; r < 4; ++r) {
                        int kv_g = kv0 + 32 * w + 16 * kvb + 4 * lg + r;
                        int q_g = Q0 + 16 * qb + li;
                        if (kv_g > q_g) s[kvb][qb][r] = -3.0e38f;
                    }
        }
        float mx[4];
        #pragma unroll
        for (int qb = 0; qb < 4; ++qb) {
            float m0_ = fmaxf(fmaxf(s[0][qb][0], s[0][qb][1]), fmaxf(s[0][qb][2], s[0][qb][3]));
            float m1_ = fmaxf(fmaxf(s[1][qb][0], s[1][qb][1]), fmaxf(s[1][qb][2], s[1][qb][3]));
            mx[qb] = fmaxf(m0_, m1_);
        }
        bool ok = (mx[0] <= m_r[0] + 8.f) && (mx[1] <= m_r[1] + 8.f) &&
                  (mx[2] <= m_r[2] + 8.f) && (mx[3] <= m_r[3] + 8.f);
        if (!__all(ok)) {
            #pragma unroll
            for (int qb = 0; qb < 4; ++qb) {
                float mxf = fmaxf(mx[qb], __shfl_xor(mx[qb], 16));
                mxf = fmaxf(mxf, __shfl_xor(mxf, 32));
                float m_new = fmaxf(m_r[qb], mxf);
                float corr = fast_exp2(m_r[qb] - m_new);
                m_r[qb] = m_new;
                l_r[qb] *= corr;
                float corrO[4];
                #pragma unroll
                for (int r = 0; r < 4; ++r)
                    corrO[r] = __shfl(corr, (lane & 48) | (4 * lg + r));
                #pragma unroll
                for (int n = 0; n < 4; ++n)
                    #pragma unroll
                    for (int r = 0; r < 4; ++r) oacc[qb][n][r] *= corrO[r];
            }
        }
        #pragma unroll
        for (int qb = 0; qb < 4; ++qb) {
            float rs = 0.f;
            #pragma unroll
            for (int kvb = 0; kvb < 2; ++kvb)
                #pragma unroll
                for (int r = 0; r < 4; ++r) {
                    float pv = fast_exp2(s[kvb][qb][r] - m_r[qb]);
                    s[kvb][qb][r] = pv;
                    rs += pv;
                }
            l_r[qb] += rs;
        }
        bf16x8 vb[4];
        #pragma unroll
        for (int n = 0; n < 4; ++n)
            vb[n] = *reinterpret_cast<const bf16x8*>(
                Tb + (16 * n + li) * 256 + ((64 * w + 16 * lg) ^ (li << 4)));
        __builtin_amdgcn_s_setprio(1);
        #pragma unroll
        for (int qb = 0; qb < 4; ++qb) {
            union { unsigned uw[4]; bf16x8 v; } pa;
            asm("v_cvt_pk_bf16_f32 %0, %1, %2" : "=v"(pa.uw[0]) : "v"(s[0][qb][0]), "v"(s[0][qb][1]));
            asm("v_cvt_pk_bf16_f32 %0, %1, %2" : "=v"(pa.uw[1]) : "v"(s[0][qb][2]), "v"(s[0][qb][3]));
            asm("v_cvt_pk_bf16_f32 %0, %1, %2" : "=v"(pa.uw[2]) : "v"(s[1][qb][0]), "v"(s[1][qb][1]));
            asm("v_cvt_pk_bf16_f32 %0, %1, %2" : "=v"(pa.uw[3]) : "v"(s[1][qb][2]), "v"(s[1][qb][3]));
            #pragma unroll
            for (int n = 0; n < 4; ++n)
                oacc[qb][n] = __builtin_amdgcn_mfma_f32_16x16x32_bf16(
                    pa.v, vb[n], oacc[qb][n], 0, 0, 0);
        }
        __builtin_amdgcn_s_setprio(0);
    };

    // single-buffer pipeline: load i+1 to regs BEFORE compute(i); write after
    // the read-barrier (T14). 2 barriers/chunk; 4 blocks/CU hide the stalls.
    ALOAD(0);
    AWRITE();
    wg_barrier();
    for (int i = 0; i < nch; ++i) {
        if (i + 1 < nch) ALOAD(i + 1);
        compute(i == nch - 1, i * 128);
        wg_barrier();               // all waves done reading chunk i
        if (i + 1 < nch) {
            AWRITE();
            wg_barrier();           // chunk i+1 visible
        }
    }

    // ---- in-block merge of the 4 wave-shards ----
    #pragma unroll
    for (int qb = 0; qb < 4; ++qb) {
        l_r[qb] += __shfl_xor(l_r[qb], 16);
        l_r[qb] += __shfl_xor(l_r[qb], 32);
    }
    if (lg == 0) {
        #pragma unroll
        for (int qb = 0; qb < 4; ++qb) {
            mw[w * 64 + 16 * qb + li] = m_r[qb];
            lw[w * 64 + 16 * qb + li] = l_r[qb];
        }
    }
    #pragma unroll
    for (int qb = 0; qb < 4; ++qb)
        #pragma unroll
        for (int r = 0; r < 4; ++r) {
            union { unsigned uw[2]; u16x4 v; } u;
            asm("v_cvt_pk_bf16_f32 %0, %1, %2" : "=v"(u.uw[0]) : "v"(oacc[qb][0][r]), "v"(oacc[qb][1][r]));
            asm("v_cvt_pk_bf16_f32 %0, %1, %2" : "=v"(u.uw[1]) : "v"(oacc[qb][2][r]), "v"(oacc[qb][3][r]));
            int q = 16 * qb + 4 * lg + r;
            *reinterpret_cast<u16x4*>(OW + (w * 64 + q) * 64 + li * 4) = u.v;
        }
    wg_barrier();

    // phase A: merge shards into registers (reads OW/mw/lw)
    float merged[16];
    {
        const int q = tid >> 2, g = tid & 3;
        float m4[4], l4[4];
        #pragma unroll
        for (int ww = 0; ww < 4; ++ww) { m4[ww] = mw[ww * 64 + q]; l4[ww] = lw[ww * 64 + q]; }
        float M = fmaxf(fmaxf(m4[0], m4[1]), fmaxf(m4[2], m4[3]));
        float cw[4], L = 0.f;
        #pragma unroll
        for (int ww = 0; ww < 4; ++ww) { cw[ww] = fast_exp2(m4[ww] - M); L += cw[ww] * l4[ww]; }
        float inv = 1.f / L;
        #pragma unroll
        for (int e = 0; e < 16; ++e) {
            float a = 0.f;
            #pragma unroll
            for (int ww = 0; ww < 4; ++ww)
                a += cw[ww] * bf2f(OW[(ww * 64 + q) * 64 + e * 4 + g]);
            merged[e] = a * inv;
        }
    }
    wg_barrier();   // all OW reads done before Ms/Wvs overlay

    // phase B: write merged -> Ms; stage Wv -> Wvs
    {
        const int q = tid >> 2, g = tid & 3;
        #pragma unroll
        for (int ee = 0; ee < 8; ++ee) {
            unsigned pk;
            asm("v_cvt_pk_bf16_f32 %0, %1, %2" : "=v"(pk) : "v"(merged[2 * ee]), "v"(merged[2 * ee + 1]));
            *reinterpret_cast<unsigned*>(reinterpret_cast<char*>(Ms) + swz(q, g * 32 + 4 * ee)) = pk;
        }
        const int r = tid >> 1, hf = tid & 1;
        const float* wp = Wv + r * 64 + hf * 32;
        #pragma unroll
        for (int qq = 0; qq < 2; ++qq) {
            f32x4 w0 = *reinterpret_cast<const f32x4*>(wp + qq * 16);
            f32x4 w1 = *reinterpret_cast<const f32x4*>(wp + qq * 16 + 4);
            f32x4 w2 = *reinterpret_cast<const f32x4*>(wp + qq * 16 + 8);
            f32x4 w3 = *reinterpret_cast<const f32x4*>(wp + qq * 16 + 12);
            u16x8 h0, h1;
            #pragma unroll
            for (int jj = 0; jj < 4; ++jj) {
                h0[jj] = f2bf(w0[jj]); h0[4 + jj] = f2bf(w1[jj]);
                h1[jj] = f2bf(w2[jj]); h1[4 + jj] = f2bf(w3[jj]);
            }
            *reinterpret_cast<u16x8*>(reinterpret_cast<char*>(Wvs) + swz(r, hf * 64 + qq * 32)) = h0;
            *reinterpret_cast<u16x8*>(reinterpret_cast<char*>(Wvs) + swz(r, hf * 64 + qq * 32 + 16)) = h1;
        }
    }
    wg_barrier();

    // out-GEMM: D[dv][q] = Wv[dv][l] * Om^T[l][q]; wave w owns dv 32w..32w+31
    f32x4 vacc[2][4];
    #pragma unroll
    for (int i = 0; i < 2; ++i)
        #pragma unroll
        for (int j = 0; j < 4; ++j) vacc[i][j] = f32x4{0.f, 0.f, 0.f, 0.f};
    #pragma unroll
    for (int c = 0; c < 2; ++c) {
        bf16x8 af[2], bfv[4];
        #pragma unroll
        for (int mf = 0; mf < 2; ++mf)
            af[mf] = *reinterpret_cast<const bf16x8*>(
                reinterpret_cast<const char*>(Wvs) + swz(32 * w + 16 * mf + li, c * 64 + lg * 16));
        #pragma unroll
        for (int nf = 0; nf < 4; ++nf)
            bfv[nf] = *reinterpret_cast<const bf16x8*>(
                reinterpret_cast<const char*>(Ms) + swz(16 * nf + li, c * 64 + lg * 16));
        #pragma unroll
        for (int mf = 0; mf < 2; ++mf)
            #pragma unroll
            for (int nf = 0; nf < 4; ++nf)
                vacc[mf][nf] = __builtin_amdgcn_mfma_f32_16x16x32_bf16(
                    af[mf], bfv[nf], vacc[mf][nf], 0, 0, 0);
    }
    wg_barrier();
    // transpose-stage Os[q][dv] then coalesced f32x4 global writes
    #pragma unroll
    for (int mf = 0; mf < 2; ++mf)
        #pragma unroll
        for (int nf = 0; nf < 4; ++nf)
            #pragma unroll
            for (int r = 0; r < 4; ++r)
                Os[(16 * nf + li) * 132 + 32 * w + 16 * mf + 4 * lg + r] = vacc[mf][nf][r];
    wg_barrier();
    {
        const int r = tid >> 2, cb = (tid & 3) * 32;
        float* op = out + ((long)b * NS + Q0 + r) * NH + cb;
        const float* sp = Os + r * 132 + cb;
        #pragma unroll
        for (int qq = 0; qq < 8; ++qq)
            *reinterpret_cast<f32x4*>(op + 4 * qq) = *reinterpret_cast<const f32x4*>(sp + 4 * qq);
    }
}

// ---------------------------------------------------------------------------
extern "C" void kernel_launch(void* const* d_in, const int* in_sizes, int n_in,
                              void* d_out, int out_size, void* d_ws, size_t ws_size,
                              hipStream_t stream) {
    const float* x    = (const float*)d_in[0];
    const float* Wdkv = (const float*)d_in[1];
    const float* Wk   = (const float*)d_in[2];
    const float* Wv   = (const float*)d_in[3];
    const float* Wq   = (const float*)d_in[4];

    float* out = (float*)d_out;
    float* latent_out = out + (long)NM * NH;   // output 1 follows output 0

    // workspace (~12.5 MB)
    ushort_t* WcatT = (ushort_t*)d_ws;                 // 512 KB
    ushort_t* q_bf  = WcatT + 128 * NE;                // 4 MB
    ushort_t* k_bf  = q_bf + (long)NM * NL;            // 4 MB
    ushort_t* kt    = k_bf + (long)NM * NL;            // 4 MB (latent^T)

    hipLaunchKernelGGL(prep_kernel, dim3(NE / 256, 4), dim3(256), 0, stream, Wdkv, Wk, Wq, WcatT);
    hipLaunchKernelGGL(proj_kernel, dim3(NM / 64), dim3(256), 0, stream,
                       x, WcatT, latent_out, k_bf, q_bf, kt);
    hipLaunchKernelGGL(attn_kernel, dim3(512), dim3(256), 0, stream,
                       q_bf, k_bf, kt, Wv, out);
}

// Round 16
// 131.794 us; speedup vs baseline: 2.5789x; 2.5789x over previous
//
#include <hip/hip_runtime.h>
#include <hip/hip_bf16.h>

#define NB 8
#define NS 4096
#define NE 2048
#define NL 64
#define NH 128
#define NM (NB*NS)

typedef unsigned short ushort_t;
typedef __attribute__((ext_vector_type(4))) float f32x4;
typedef __attribute__((ext_vector_type(8))) __bf16 bf16x8;
typedef __attribute__((ext_vector_type(8))) unsigned short u16x8;
typedef __attribute__((ext_vector_type(4))) unsigned short u16x4;

// 128^-0.5 * log2(e): folded into absorbed-q weights so attn uses exp2 directly
#define SCALE2 0.1275174537f

__device__ __forceinline__ float fast_exp2(float x) {
    return __builtin_amdgcn_exp2f(x);   // v_exp_f32: D = 2^S0
}

__device__ __forceinline__ unsigned short f2bf(float f) {
    union { float f; unsigned u; } v; v.f = f;
    unsigned u = v.u + 0x7fffu + ((v.u >> 16) & 1u);
    return (unsigned short)(u >> 16);
}

__device__ __forceinline__ float bf2f(ushort_t u) {
    union { unsigned u; float f; } v; v.u = (unsigned)u << 16; return v.f;
}

// XOR swizzle for 128-byte-stride LDS tiles (G4)
__device__ __forceinline__ int swz(int row, int colbyte) {
    return (row * 128 + colbyte) ^ ((row & 7) << 4);
}

// Raw barrier: LDS visibility only — does NOT drain vmcnt (T4).
__device__ __forceinline__ void wg_barrier() {
    asm volatile("s_waitcnt lgkmcnt(0)" ::: "memory");
    __builtin_amdgcn_s_barrier();
    __builtin_amdgcn_sched_barrier(0);
}

// ---------------------------------------------------------------------------
// prep: WcatT[128][2048] bf16.  rows 0..63 = W_dkv, rows 64..127 = absorbed^T * SCALE2
// ---------------------------------------------------------------------------
__global__ __launch_bounds__(256) void prep_kernel(
    const float* __restrict__ Wdkv, const float* __restrict__ Wk,
    const float* __restrict__ Wq, ushort_t* __restrict__ WcatT)
{
    __shared__ float wk[128 * 64];
    const int t = threadIdx.x;
    for (int i = t; i < 128 * 64; i += 256) wk[i] = Wk[i];
    __syncthreads();
    const int e = blockIdx.x * 256 + t;
    const int l0 = blockIdx.y * 16;
    float acc[16];
    #pragma unroll
    for (int l = 0; l < 16; ++l) acc[l] = 0.f;
    for (int h = 0; h < 128; ++h) {
        float q = Wq[h * NE + e];
        #pragma unroll
        for (int l = 0; l < 16; ++l) acc[l] += q * wk[h * 64 + l0 + l];
    }
    for (int l = 0; l < 16; ++l) WcatT[(64 + l0 + l) * NE + e] = f2bf(acc[l] * SCALE2);
    for (int l = 0; l < 16; ++l) WcatT[(l0 + l) * NE + e] = f2bf(Wdkv[(l0 + l) * NE + e]);
}

// ---------------------------------------------------------------------------
// proj: Y[M,128] = x[M,2048] @ WcatT^T.  BM=64,BN=128,BK=64, 4 waves (2x2).
// Depth-2 ping-pong register prefetch + raw barriers.
// Epilogue: latent(f32) + k(bf16) + q(bf16) + kt = latent^T (identity MFMA).
// (Measured R11: ~50 us, ~90% of its 45 us HBM floor — frozen.)
// ---------------------------------------------------------------------------
__global__ __launch_bounds__(256) void proj_kernel(
    const float* __restrict__ x, const ushort_t* __restrict__ WcatT,
    float* __restrict__ latent_out, ushort_t* __restrict__ k_bf,
    ushort_t* __restrict__ q_bf, ushort_t* __restrict__ kt)
{
    __shared__ ushort_t As[2][64 * 64];
    __shared__ ushort_t Bs[2][128 * 64];
    const int tid = threadIdx.x;
    const int w = tid >> 6, lane = tid & 63, lg = lane >> 4, li = lane & 15;
    const int m0 = blockIdx.x * 64;
    const int wm = (w >> 1) * 32, wn = (w & 1) * 64;
    const int srow = tid >> 3, scol = tid & 7;

    f32x4 acc[2][4];
    #pragma unroll
    for (int i = 0; i < 2; ++i)
        #pragma unroll
        for (int j = 0; j < 4; ++j) acc[i][j] = f32x4{0.f, 0.f, 0.f, 0.f};

    f32x4 a0reg[2][2], a1reg[2][2];
    u16x8 b0reg[4], b1reg[4];

#define PLOAD(k0, AR, BR) do { \
    _Pragma("unroll") for (int p = 0; p < 2; ++p) { \
        const float* gp = x + (long)(m0 + srow + 32 * p) * NE + (k0) + scol * 8; \
        AR[p][0] = *reinterpret_cast<const f32x4*>(gp); \
        AR[p][1] = *reinterpret_cast<const f32x4*>(gp + 4); } \
    _Pragma("unroll") for (int p = 0; p < 4; ++p) \
        BR[p] = *reinterpret_cast<const u16x8*>(WcatT + (long)(srow + 32 * p) * NE + (k0) + scol * 8); \
} while (0)

#define PWRITE(AR, BR, buf) do { \
    _Pragma("unroll") for (int p = 0; p < 2; ++p) { \
        union { unsigned uw[4]; u16x8 v; } hu; \
        asm("v_cvt_pk_bf16_f32 %0, %1, %2" : "=v"(hu.uw[0]) : "v"(AR[p][0][0]), "v"(AR[p][0][1])); \
        asm("v_cvt_pk_bf16_f32 %0, %1, %2" : "=v"(hu.uw[1]) : "v"(AR[p][0][2]), "v"(AR[p][0][3])); \
        asm("v_cvt_pk_bf16_f32 %0, %1, %2" : "=v"(hu.uw[2]) : "v"(AR[p][1][0]), "v"(AR[p][1][1])); \
        asm("v_cvt_pk_bf16_f32 %0, %1, %2" : "=v"(hu.uw[3]) : "v"(AR[p][1][2]), "v"(AR[p][1][3])); \
        *reinterpret_cast<u16x8*>(reinterpret_cast<char*>(As[buf]) + swz(srow + 32 * p, scol * 16)) = hu.v; } \
    _Pragma("unroll") for (int p = 0; p < 4; ++p) \
        *reinterpret_cast<u16x8*>(reinterpret_cast<char*>(Bs[buf]) + swz(srow + 32 * p, scol * 16)) = BR[p]; \
} while (0)

    auto compute = [&](int buf) {
        #pragma unroll
        for (int c = 0; c < 2; ++c) {
            bf16x8 af[2], bfv[4];
            #pragma unroll
            for (int mf = 0; mf < 2; ++mf)
                af[mf] = *reinterpret_cast<const bf16x8*>(
                    reinterpret_cast<const char*>(As[buf]) + swz(wm + 16 * mf + li, c * 64 + lg * 16));
            #pragma unroll
            for (int nf = 0; nf < 4; ++nf)
                bfv[nf] = *reinterpret_cast<const bf16x8*>(
                    reinterpret_cast<const char*>(Bs[buf]) + swz(wn + 16 * nf + li, c * 64 + lg * 16));
            #pragma unroll
            for (int mf = 0; mf < 2; ++mf)
                #pragma unroll
                for (int nf = 0; nf < 4; ++nf)
                    acc[mf][nf] = __builtin_amdgcn_mfma_f32_16x16x32_bf16(
                        af[mf], bfv[nf], acc[mf][nf], 0, 0, 0);
        }
    };

    PLOAD(0, a0reg, b0reg);
    PLOAD(64, a1reg, b1reg);
    PWRITE(a0reg, b0reg, 0);
    wg_barrier();

    for (int ks = 0; ks < 32; ks += 2) {
        if (ks + 2 < 32) PLOAD((ks + 2) * 64, a0reg, b0reg);
        compute(0);
        PWRITE(a1reg, b1reg, 1);
        wg_barrier();
        if (ks + 3 < 32) PLOAD((ks + 3) * 64, a1reg, b1reg);
        compute(1);
        if (ks + 2 < 32) PWRITE(a0reg, b0reg, 0);
        wg_barrier();
    }

    const int b = m0 >> 12, s0 = m0 & 4095;
    #pragma unroll
    for (int mf = 0; mf < 2; ++mf) {
        #pragma unroll
        for (int nf = 0; nf < 4; ++nf) {
            int col = wn + 16 * nf + li;
            #pragma unroll
            for (int r = 0; r < 4; ++r) {
                int row = m0 + wm + 16 * mf + 4 * lg + r;
                float v = acc[mf][nf][r];
                if (wn == 0) {
                    latent_out[(long)row * NL + col] = v;
                    k_bf[(long)row * NL + col] = f2bf(v);
                    *reinterpret_cast<ushort_t*>(reinterpret_cast<char*>(As[0]) +
                        swz(wm + 16 * mf + 4 * lg + r, col * 2)) = f2bf(v);
                } else {
                    q_bf[(long)row * NL + (col - 64)] = f2bf(v);
                }
            }
        }
    }
    wg_barrier();
    // kt-GEMM: kt[l][s] = latent^T via A = identity fragment.
    union { u16x8 u; bf16x8 v; } iu;
    #pragma unroll
    for (int j = 0; j < 8; ++j)
        iu.u[j] = (lg == (li >> 3) + 2 * (w & 1) && (li & 7) == j)
                      ? (ushort_t)0x3F80 : (ushort_t)0;
    const int ckt = w >> 1;
    f32x4 ktacc[4];
    #pragma unroll
    for (int nf = 0; nf < 4; ++nf) {
        bf16x8 bfv = *reinterpret_cast<const bf16x8*>(
            reinterpret_cast<const char*>(As[0]) + swz(16 * nf + li, ckt * 64 + lg * 16));
        ktacc[nf] = __builtin_amdgcn_mfma_f32_16x16x32_bf16(
            iu.v, bfv, f32x4{0.f, 0.f, 0.f, 0.f}, 0, 0, 0);
    }
    #pragma unroll
    for (int nf = 0; nf < 4; ++nf)
        #pragma unroll
        for (int r = 0; r < 4; ++r)
            kt[(long)(b * 64 + 16 * w + 4 * lg + r) * NS + s0 + 16 * nf + li] =
                f2bf(ktacc[nf][r]);
}

// ---------------------------------------------------------------------------
// attn: R9 math/layouts with 34.8KB LDS (single-buffered Ks+KTs, T14 staging,
// 2 barriers/chunk). __launch_bounds__(256,2): empirically arg=2 -> 128-VGPR
// cap (no spill; R15's arg=4 -> 64-VGPR cap -> 0.6GB scratch traffic).
// Occupancy: VGPR<=128 (16 waves/CU) and LDS 34.8K (4 blocks/CU) coincide.
// ---------------------------------------------------------------------------
__global__ __launch_bounds__(256, 2) void attn_kernel(
    const ushort_t* __restrict__ q_bf, const ushort_t* __restrict__ k_bf,
    const ushort_t* __restrict__ kt, const float* __restrict__ Wv,
    float* __restrict__ out)
{
    __shared__ __attribute__((aligned(16))) char smem[34816];
    // main loop: Ks @ 0 (16K, [128][64] swizzled); KTs @ 16K (16K, [64][128] kv'-permuted)
    // epilogue:  OW bf16 [4][64][64] @ 0 (32K); mw @ 32768; lw @ 33792
    //            then (after read-fence): Ms @ 0 (8K); Wvs @ 8192 (16K)
    //            then Os f32 [64][132] @ 0 (33792 B)
    ushort_t* OW = (ushort_t*)smem;
    float* mw = (float*)(smem + 32768);
    float* lw = (float*)(smem + 33792);
    ushort_t* Ms = (ushort_t*)smem;
    ushort_t* Wvs = (ushort_t*)(smem + 8192);
    float* Os = (float*)smem;

    const int tid = threadIdx.x;
    const int w = tid >> 6, lane = tid & 63, lg = lane >> 4, li = lane & 15;
    const int l = blockIdx.x;
    const int b = l & 7;
    const int p_ = l >> 3;
    // balanced qt permutation (R5-validated under both XCD dispatch policies)
    const int k_ = p_ >> 1, e_ = p_ & 1, kk = (k_ & 15) * 2;
    const int qt = (k_ >> 4) ? (e_ ? kk + 1 : 63 - kk) : (e_ ? 62 - kk : kk);
    const int Q0 = qt << 6;
    const int nch = (qt >> 1) + 1;       // 128-kv chunks

    const int krow = tid >> 1, khalf = tid & 1;      // K: [128][64]
    const int trow = tid >> 2, tkq = (tid & 3) * 32; // KT: [64][128]

    bf16x8 qf[4][2];
    #pragma unroll
    for (int qb = 0; qb < 4; ++qb)
        #pragma unroll
        for (int c = 0; c < 2; ++c)
            qf[qb][c] = *reinterpret_cast<const bf16x8*>(
                q_bf + ((long)b * NS + Q0 + 16 * qb + li) * NL + c * 32 + lg * 8);

    float m_r[4], l_r[4];
    #pragma unroll
    for (int qb = 0; qb < 4; ++qb) { m_r[qb] = -1.0e30f; l_r[qb] = 0.f; }
    f32x4 oacc[4][4];
    #pragma unroll
    for (int qb = 0; qb < 4; ++qb)
        #pragma unroll
        for (int n = 0; n < 4; ++n) oacc[qb][n] = f32x4{0.f, 0.f, 0.f, 0.f};

    u16x8 kreg[4], treg[4];   // single staging set (T14 issue-early/write-late)

#define ALOAD(ch) do { \
    const int kv0_ = (ch) * 128; \
    _Pragma("unroll") for (int pp = 0; pp < 4; ++pp) \
        kreg[pp] = *reinterpret_cast<const u16x8*>( \
            k_bf + ((long)b * NS + kv0_ + krow) * NL + khalf * 32 + pp * 8); \
    _Pragma("unroll") for (int pp = 0; pp < 4; ++pp) \
        treg[pp] = *reinterpret_cast<const u16x8*>( \
            kt + ((long)b * 64 + trow) * NS + kv0_ + tkq + pp * 8); \
} while (0)

#define AWRITE() do { \
    char* Kb_ = smem; \
    char* Tb_ = smem + 16384; \
    _Pragma("unroll") for (int pp = 0; pp < 4; ++pp) \
        *reinterpret_cast<u16x8*>(Kb_ + swz(krow, khalf * 64 + pp * 16)) = kreg[pp]; \
    _Pragma("unroll") for (int pp = 0; pp < 4; ++pp) { \
        const int kv8 = tkq + pp * 8; \
        const int colp = (kv8 & 0x60) | ((kv8 & 0xC) << 1) | ((kv8 & 0x10) >> 2); \
        const int xo = (trow & 15) << 4; \
        u16x4 lo = {treg[pp][0], treg[pp][1], treg[pp][2], treg[pp][3]}; \
        u16x4 hi = {treg[pp][4], treg[pp][5], treg[pp][6], treg[pp][7]}; \
        *reinterpret_cast<u16x4*>(Tb_ + trow * 256 + ((colp * 2) ^ xo)) = lo; \
        *reinterpret_cast<u16x4*>(Tb_ + trow * 256 + (((colp + 8) * 2) ^ xo)) = hi; \
    } \
} while (0)

    auto compute = [&](bool diag, int kv0) {
        const char* Kb = smem;
        const char* Tb = smem + 16384;
        f32x4 s[2][4];
        #pragma unroll
        for (int kvb = 0; kvb < 2; ++kvb)
            #pragma unroll
            for (int qb = 0; qb < 4; ++qb) s[kvb][qb] = f32x4{0.f, 0.f, 0.f, 0.f};
        __builtin_amdgcn_s_setprio(1);
        #pragma unroll
        for (int c = 0; c < 2; ++c)
            #pragma unroll
            for (int kvb = 0; kvb < 2; ++kvb) {
                bf16x8 a = *reinterpret_cast<const bf16x8*>(
                    Kb + swz(32 * w + 16 * kvb + li, c * 64 + lg * 16));
                #pragma unroll
                for (int qb = 0; qb < 4; ++qb)
                    s[kvb][qb] = __builtin_amdgcn_mfma_f32_16x16x32_bf16(
                        a, qf[qb][c], s[kvb][qb], 0, 0, 0);
            }
        __builtin_amdgcn_s_setprio(0);
        if (diag) {
            #pragma unroll
            for (int kvb = 0; kvb < 2; ++kvb)
                #pragma unroll
                for (int qb = 0; qb < 4; ++qb)
                    #pragma unroll
                    for (int r = 0; r < 4; ++r) {
                        int kv_g = kv0 + 32 * w + 16 * kvb + 4 * lg + r;
                        int q_g = Q0 + 16 * qb + li;
                        if (kv_g > q_g) s[kvb][qb][r] = -3.0e38f;
                    }
        }
        float mx[4];
        #pragma unroll
        for (int qb = 0; qb < 4; ++qb) {
            float m0_ = fmaxf(fmaxf(s[0][qb][0], s[0][qb][1]), fmaxf(s[0][qb][2], s[0][qb][3]));
            float m1_ = fmaxf(fmaxf(s[1][qb][0], s[1][qb][1]), fmaxf(s[1][qb][2], s[1][qb][3]));
            mx[qb] = fmaxf(m0_, m1_);
        }
        bool ok = (mx[0] <= m_r[0] + 8.f) && (mx[1] <= m_r[1] + 8.f) &&
                  (mx[2] <= m_r[2] + 8.f) && (mx[3] <= m_r[3] + 8.f);
        if (!__all(ok)) {
            #pragma unroll
            for (int qb = 0; qb < 4; ++qb) {
                float mxf = fmaxf(mx[qb], __shfl_xor(mx[qb], 16));
                mxf = fmaxf(mxf, __shfl_xor(mxf, 32));
                float m_new = fmaxf(m_r[qb], mxf);
                float corr = fast_exp2(m_r[qb] - m_new);
                m_r[qb] = m_new;
                l_r[qb] *= corr;
                float corrO[4];
                #pragma unroll
                for (int r = 0; r < 4; ++r)
                    corrO[r] = __shfl(corr, (lane & 48) | (4 * lg + r));
                #pragma unroll
                for (int n = 0; n < 4; ++n)
                    #pragma unroll
                    for (int r = 0; r < 4; ++r) oacc[qb][n][r] *= corrO[r];
            }
        }
        #pragma unroll
        for (int qb = 0; qb < 4; ++qb) {
            float rs = 0.f;
            #pragma unroll
            for (int kvb = 0; kvb < 2; ++kvb)
                #pragma unroll
                for (int r = 0; r < 4; ++r) {
                    float pv = fast_exp2(s[kvb][qb][r] - m_r[qb]);
                    s[kvb][qb][r] = pv;
                    rs += pv;
                }
            l_r[qb] += rs;
        }
        bf16x8 vb[4];
        #pragma unroll
        for (int n = 0; n < 4; ++n)
            vb[n] = *reinterpret_cast<const bf16x8*>(
                Tb + (16 * n + li) * 256 + ((64 * w + 16 * lg) ^ (li << 4)));
        __builtin_amdgcn_s_setprio(1);
        #pragma unroll
        for (int qb = 0; qb < 4; ++qb) {
            union { unsigned uw[4]; bf16x8 v; } pa;
            asm("v_cvt_pk_bf16_f32 %0, %1, %2" : "=v"(pa.uw[0]) : "v"(s[0][qb][0]), "v"(s[0][qb][1]));
            asm("v_cvt_pk_bf16_f32 %0, %1, %2" : "=v"(pa.uw[1]) : "v"(s[0][qb][2]), "v"(s[0][qb][3]));
            asm("v_cvt_pk_bf16_f32 %0, %1, %2" : "=v"(pa.uw[2]) : "v"(s[1][qb][0]), "v"(s[1][qb][1]));
            asm("v_cvt_pk_bf16_f32 %0, %1, %2" : "=v"(pa.uw[3]) : "v"(s[1][qb][2]), "v"(s[1][qb][3]));
            #pragma unroll
            for (int n = 0; n < 4; ++n)
                oacc[qb][n] = __builtin_amdgcn_mfma_f32_16x16x32_bf16(
                    pa.v, vb[n], oacc[qb][n], 0, 0, 0);
        }
        __builtin_amdgcn_s_setprio(0);
    };

    // single-buffer pipeline: load i+1 to regs BEFORE compute(i); write after
    // the read-barrier (T14). 2 barriers/chunk; 4 blocks/CU hide the stalls.
    ALOAD(0);
    AWRITE();
    wg_barrier();
    for (int i = 0; i < nch; ++i) {
        if (i + 1 < nch) ALOAD(i + 1);
        compute(i == nch - 1, i * 128);
        wg_barrier();               // all waves done reading chunk i
        if (i + 1 < nch) {
            AWRITE();
            wg_barrier();           // chunk i+1 visible
        }
    }

    // ---- in-block merge of the 4 wave-shards ----
    #pragma unroll
    for (int qb = 0; qb < 4; ++qb) {
        l_r[qb] += __shfl_xor(l_r[qb], 16);
        l_r[qb] += __shfl_xor(l_r[qb], 32);
    }
    if (lg == 0) {
        #pragma unroll
        for (int qb = 0; qb < 4; ++qb) {
            mw[w * 64 + 16 * qb + li] = m_r[qb];
            lw[w * 64 + 16 * qb + li] = l_r[qb];
        }
    }
    #pragma unroll
    for (int qb = 0; qb < 4; ++qb)
        #pragma unroll
        for (int r = 0; r < 4; ++r) {
            union { unsigned uw[2]; u16x4 v; } u;
            asm("v_cvt_pk_bf16_f32 %0, %1, %2" : "=v"(u.uw[0]) : "v"(oacc[qb][0][r]), "v"(oacc[qb][1][r]));
            asm("v_cvt_pk_bf16_f32 %0, %1, %2" : "=v"(u.uw[1]) : "v"(oacc[qb][2][r]), "v"(oacc[qb][3][r]));
            int q = 16 * qb + 4 * lg + r;
            *reinterpret_cast<u16x4*>(OW + (w * 64 + q) * 64 + li * 4) = u.v;
        }
    wg_barrier();

    // phase A: merge shards into registers (reads OW/mw/lw)
    float merged[16];
    {
        const int q = tid >> 2, g = tid & 3;
        float m4[4], l4[4];
        #pragma unroll
        for (int ww = 0; ww < 4; ++ww) { m4[ww] = mw[ww * 64 + q]; l4[ww] = lw[ww * 64 + q]; }
        float M = fmaxf(fmaxf(m4[0], m4[1]), fmaxf(m4[2], m4[3]));
        float cw[4], L = 0.f;
        #pragma unroll
        for (int ww = 0; ww < 4; ++ww) { cw[ww] = fast_exp2(m4[ww] - M); L += cw[ww] * l4[ww]; }
        float inv = 1.f / L;
        #pragma unroll
        for (int e = 0; e < 16; ++e) {
            float a = 0.f;
            #pragma unroll
            for (int ww = 0; ww < 4; ++ww)
                a += cw[ww] * bf2f(OW[(ww * 64 + q) * 64 + e * 4 + g]);
            merged[e] = a * inv;
        }
    }
    wg_barrier();   // all OW reads done before Ms/Wvs overlay

    // phase B: write merged -> Ms; stage Wv -> Wvs
    {
        const int q = tid >> 2, g = tid & 3;
        #pragma unroll
        for (int ee = 0; ee < 8; ++ee) {
            unsigned pk;
            asm("v_cvt_pk_bf16_f32 %0, %1, %2" : "=v"(pk) : "v"(merged[2 * ee]), "v"(merged[2 * ee + 1]));
            *reinterpret_cast<unsigned*>(reinterpret_cast<char*>(Ms) + swz(q, g * 32 + 4 * ee)) = pk;
        }
        const int r = tid >> 1, hf = tid & 1;
        const float* wp = Wv + r * 64 + hf * 32;
        #pragma unroll
        for (int qq = 0; qq < 2; ++qq) {
            f32x4 w0 = *reinterpret_cast<const f32x4*>(wp + qq * 16);
            f32x4 w1 = *reinterpret_cast<const f32x4*>(wp + qq * 16 + 4);
            f32x4 w2 = *reinterpret_cast<const f32x4*>(wp + qq * 16 + 8);
            f32x4 w3 = *reinterpret_cast<const f32x4*>(wp + qq * 16 + 12);
            u16x8 h0, h1;
            #pragma unroll
            for (int jj = 0; jj < 4; ++jj) {
                h0[jj] = f2bf(w0[jj]); h0[4 + jj] = f2bf(w1[jj]);
                h1[jj] = f2bf(w2[jj]); h1[4 + jj] = f2bf(w3[jj]);
            }
            *reinterpret_cast<u16x8*>(reinterpret_cast<char*>(Wvs) + swz(r, hf * 64 + qq * 32)) = h0;
            *reinterpret_cast<u16x8*>(reinterpret_cast<char*>(Wvs) + swz(r, hf * 64 + qq * 32 + 16)) = h1;
        }
    }
    wg_barrier();

    // out-GEMM: D[dv][q] = Wv[dv][l] * Om^T[l][q]; wave w owns dv 32w..32w+31
    f32x4 vacc[2][4];
    #pragma unroll
    for (int i = 0; i < 2; ++i)
        #pragma unroll
        for (int j = 0; j < 4; ++j) vacc[i][j] = f32x4{0.f, 0.f, 0.f, 0.f};
    #pragma unroll
    for (int c = 0; c < 2; ++c) {
        bf16x8 af[2], bfv[4];
        #pragma unroll
        for (int mf = 0; mf < 2; ++mf)
            af[mf] = *reinterpret_cast<const bf16x8*>(
                reinterpret_cast<const char*>(Wvs) + swz(32 * w + 16 * mf + li, c * 64 + lg * 16));
        #pragma unroll
        for (int nf = 0; nf < 4; ++nf)
            bfv[nf] = *reinterpret_cast<const bf16x8*>(
                reinterpret_cast<const char*>(Ms) + swz(16 * nf + li, c * 64 + lg * 16));
        #pragma unroll
        for (int mf = 0; mf < 2; ++mf)
            #pragma unroll
            for (int nf = 0; nf < 4; ++nf)
                vacc[mf][nf] = __builtin_amdgcn_mfma_f32_16x16x32_bf16(
                    af[mf], bfv[nf], vacc[mf][nf], 0, 0, 0);
    }
    wg_barrier();
    // transpose-stage Os[q][dv] then coalesced f32x4 global writes
    #pragma unroll
    for (int mf = 0; mf < 2; ++mf)
        #pragma unroll
        for (int nf = 0; nf < 4; ++nf)
            #pragma unroll
            for (int r = 0; r < 4; ++r)
                Os[(16 * nf + li) * 132 + 32 * w + 16 * mf + 4 * lg + r] = vacc[mf][nf][r];
    wg_barrier();
    {
        const int r = tid >> 2, cb = (tid & 3) * 32;
        float* op = out + ((long)b * NS + Q0 + r) * NH + cb;
        const float* sp = Os + r * 132 + cb;
        #pragma unroll
        for (int qq = 0; qq < 8; ++qq)
            *reinterpret_cast<f32x4*>(op + 4 * qq) = *reinterpret_cast<const f32x4*>(sp + 4 * qq);
    }
}

// ---------------------------------------------------------------------------
extern "C" void kernel_launch(void* const* d_in, const int* in_sizes, int n_in,
                              void* d_out, int out_size, void* d_ws, size_t ws_size,
                              hipStream_t stream) {
    const float* x    = (const float*)d_in[0];
    const float* Wdkv = (const float*)d_in[1];
    const float* Wk   = (const float*)d_in[2];
    const float* Wv   = (const float*)d_in[3];
    const float* Wq   = (const float*)d_in[4];

    float* out = (float*)d_out;
    float* latent_out = out + (long)NM * NH;   // output 1 follows output 0

    // workspace (~12.5 MB)
    ushort_t* WcatT = (ushort_t*)d_ws;                 // 512 KB
    ushort_t* q_bf  = WcatT + 128 * NE;                // 4 MB
    ushort_t* k_bf  = q_bf + (long)NM * NL;            // 4 MB
    ushort_t* kt    = k_bf + (long)NM * NL;            // 4 MB (latent^T)

    hipLaunchKernelGGL(prep_kernel, dim3(NE / 256, 4), dim3(256), 0, stream, Wdkv, Wk, Wq, WcatT);
    hipLaunchKernelGGL(proj_kernel, dim3(NM / 64), dim3(256), 0, stream,
                       x, WcatT, latent_out, k_bf, q_bf, kt);
    hipLaunchKernelGGL(attn_kernel, dim3(512), dim3(256), 0, stream,
                       q_bf, k_bf, kt, Wv, out);
}